// Round 1
// baseline (109.798 us; speedup 1.0000x reference)
//
#include <hip/hip_runtime.h>

#define EPS 1e-7f

constexpr int NPRED = 8192;
constexpr int NTGT  = 4096;
constexpr int BLOCK = 256;           // 4 waves
constexpr int PW    = 4;             // preds per wave
constexpr int WAVES = BLOCK / 64;    // 4
constexpr int PPB   = WAVES * PW;    // 16 preds per block
constexpr int CHUNK = 1024;          // targets staged per LDS pass (16 KB)

__global__ __launch_bounds__(BLOCK)
void diou_main(const float4* __restrict__ pred,
               const float4* __restrict__ tgt,
               float* __restrict__ acc) {
  __shared__ float4 sT[CHUNK];
  const int lane  = threadIdx.x & 63;
  const int wave  = threadIdx.x >> 6;
  const int pbase = blockIdx.x * PPB + wave * PW;

  float4 p[PW];
  float  pa[PW];
  float  bestV[PW];
  int    bestI[PW];
#pragma unroll
  for (int i = 0; i < PW; ++i) {
    p[i]     = pred[pbase + i];
    pa[i]    = (p[i].z - p[i].x) * (p[i].w - p[i].y);  // xyxy-interp area
    bestV[i] = -INFINITY;
    bestI[i] = 0;
  }

  for (int c = 0; c < NTGT; c += CHUNK) {
    __syncthreads();
    for (int t = threadIdx.x; t < CHUNK; t += BLOCK) sT[t] = tgt[c + t];
    __syncthreads();
#pragma unroll 4
    for (int t = lane; t < CHUNK; t += 64) {
      float4 tb = sT[t];
      float  ta = (tb.z - tb.x) * (tb.w - tb.y);
      int    idx = c + t;
#pragma unroll
      for (int i = 0; i < PW; ++i) {
        float w = fminf(p[i].z, tb.z) - fmaxf(p[i].x, tb.x);
        float h = fminf(p[i].w, tb.w) - fmaxf(p[i].y, tb.y);
        w = fmaxf(w, 0.f);
        h = fmaxf(h, 0.f);
        float inter = w * h;
        float iou   = inter / (pa[i] + ta - inter + EPS);
        // strict > keeps the FIRST max within a lane (indices ascend)
        if (iou > bestV[i]) { bestV[i] = iou; bestI[i] = idx; }
      }
    }
  }

  // cross-lane argmax: larger value wins; tie -> smaller index (jnp.argmax)
#pragma unroll
  for (int i = 0; i < PW; ++i) {
    float v  = bestV[i];
    int   ix = bestI[i];
    for (int off = 32; off > 0; off >>= 1) {
      float ov = __shfl_down(v, off, 64);
      int   oi = __shfl_down(ix, off, 64);
      if (ov > v || (ov == v && oi < ix)) { v = ov; ix = oi; }
    }
    bestV[i] = v;
    bestI[i] = ix;
  }

  if (lane == 0) {
    float local = 0.f;
#pragma unroll
    for (int i = 0; i < PW; ++i) {
      float4 t = tgt[bestI[i]];
      // reference reinterprets columns as (cx, cy, w, h)
      float phw = 0.5f * p[i].z, phh = 0.5f * p[i].w;
      float thw = 0.5f * t.z,    thh = 0.5f * t.w;
      float pltx = p[i].x - phw, plty = p[i].y - phh;
      float prbx = p[i].x + phw, prby = p[i].y + phh;
      float tltx = t.x - thw,    tlty = t.y - thh;
      float trbx = t.x + thw,    trby = t.y + thh;

      float iw = fmaxf(fminf(prbx, trbx) - fmaxf(pltx, tltx), 0.f);
      float ih = fmaxf(fminf(prby, trby) - fmaxf(plty, tlty), 0.f);
      float inter = iw * ih;
      float parea = p[i].z * p[i].w;
      float tarea = t.z * t.w;
      float iou   = inter / (parea + tarea - inter + EPS);

      float dx = p[i].x - t.x, dy = p[i].y - t.y;
      float cd = dx * dx + dy * dy;

      float ew = fmaxf(prbx, trbx) - fminf(pltx, tltx);
      float eh = fmaxf(prby, trby) - fminf(plty, tlty);
      float diag = ew * ew + eh * eh;

      local += iou - cd / (diag + EPS);
    }
    atomicAdd(acc, local);
  }
}

__global__ void diou_finalize(const float* __restrict__ acc,
                              float* __restrict__ out) {
  out[0] = 1.f - acc[0] * (1.f / (float)NPRED);
}

extern "C" void kernel_launch(void* const* d_in, const int* in_sizes, int n_in,
                              void* d_out, int out_size, void* d_ws, size_t ws_size,
                              hipStream_t stream) {
  const float4* pred = (const float4*)d_in[0];
  const float4* tgt  = (const float4*)d_in[1];
  float* acc = (float*)d_ws;

  hipMemsetAsync(acc, 0, sizeof(float), stream);
  diou_main<<<NPRED / PPB, BLOCK, 0, stream>>>(pred, tgt, acc);
  diou_finalize<<<1, 1, 0, stream>>>(acc, (float*)d_out);
}

// Round 2
// 81.452 us; speedup vs baseline: 1.3480x; 1.3480x over previous
//
#include <hip/hip_runtime.h>

#define EPS 1e-7f

constexpr int NPRED  = 8192;
constexpr int NTGT   = 4096;
constexpr int BLOCK  = 256;          // 4 waves
constexpr int PW     = 4;            // preds per wave
constexpr int PPB    = 16;           // preds per block (4 waves * 4)
constexpr int TSPLIT = 4;            // target quarters
constexpr int TCHUNK = NTGT / TSPLIT;    // 1024 targets per block (16 KB LDS)
constexpr int GRID_P = NPRED / PPB;      // 512
constexpr int GRID   = GRID_P * TSPLIT;  // 2048 blocks -> 8/CU

__device__ __forceinline__ unsigned sortable_key(float f) {
  unsigned b = __float_as_uint(f);
  return (b & 0x80000000u) ? ~b : (b | 0x80000000u);
}

__global__ __launch_bounds__(BLOCK)
void diou_argmax(const float4* __restrict__ pred,
                 const float4* __restrict__ tgt,
                 unsigned long long* __restrict__ pk) {
  __shared__ float4 sT[TCHUNK];
  const int lane  = threadIdx.x & 63;
  const int wave  = threadIdx.x >> 6;
  const int pblk  = blockIdx.x % GRID_P;
  const int tq    = blockIdx.x / GRID_P;
  const int tbase = tq * TCHUNK;
  const int pbase = pblk * PPB + wave * PW;

  // stage this block's target quarter (16 KB) once
  for (int t = threadIdx.x; t < TCHUNK; t += BLOCK) sT[t] = tgt[tbase + t];

  float4 p[PW];
  float  paeps[PW];
  float  bestV[PW];
  int    bestI[PW];
#pragma unroll
  for (int i = 0; i < PW; ++i) {
    p[i]     = pred[pbase + i];
    paeps[i] = (p[i].z - p[i].x) * (p[i].w - p[i].y) + EPS;  // xyxy-interp area + eps
    bestV[i] = -INFINITY;
    bestI[i] = 0;
  }
  __syncthreads();

  for (int t0 = 0; t0 < TCHUNK; t0 += 64) {
    const int t = t0 + lane;
    float4 tb = sT[t];
    float  ta = (tb.z - tb.x) * (tb.w - tb.y);
    int    idx = tbase + t;
#pragma unroll
    for (int i = 0; i < PW; ++i) {
      float w = fminf(p[i].z, tb.z) - fmaxf(p[i].x, tb.x);
      float h = fminf(p[i].w, tb.w) - fmaxf(p[i].y, tb.y);
      w = fmaxf(w, 0.f);
      h = fmaxf(h, 0.f);
      float inter = w * h;
      float denom = (paeps[i] + ta) - inter;
      float iou   = inter * __builtin_amdgcn_rcpf(denom);
      iou += 0.0f;                       // normalize -0 -> +0 (tie semantics)
      // strict > keeps the FIRST max within a lane (indices ascend)
      if (iou > bestV[i]) { bestV[i] = iou; bestI[i] = idx; }
    }
  }

  // cross-lane argmax: larger value wins; tie -> smaller index
#pragma unroll
  for (int i = 0; i < PW; ++i) {
    float v  = bestV[i];
    int   ix = bestI[i];
    for (int off = 32; off > 0; off >>= 1) {
      float ov = __shfl_down(v, off, 64);
      int   oi = __shfl_down(ix, off, 64);
      if (ov > v || (ov == v && oi < ix)) { v = ov; ix = oi; }
    }
    if (lane == 0) {
      unsigned long long packed =
          ((unsigned long long)sortable_key(v) << 32) |
          (unsigned)(NTGT - 1 - ix);                    // tie -> smaller index
      atomicMax(&pk[pbase + i], packed);
    }
  }
}

__global__ __launch_bounds__(BLOCK)
void diou_gather(const float4* __restrict__ pred,
                 const float4* __restrict__ tgt,
                 const unsigned long long* __restrict__ pk,
                 float* __restrict__ acc) {
  const int tid  = blockIdx.x * BLOCK + threadIdx.x;
  const int lane = threadIdx.x & 63;

  float4 p  = pred[tid];
  int    ix = NTGT - 1 - (unsigned)(pk[tid] & 0xFFFFFFFFu);
  float4 t  = tgt[ix];

  // reference reinterprets columns as (cx, cy, w, h)
  float phw = 0.5f * p.z, phh = 0.5f * p.w;
  float thw = 0.5f * t.z, thh = 0.5f * t.w;
  float pltx = p.x - phw, plty = p.y - phh;
  float prbx = p.x + phw, prby = p.y + phh;
  float tltx = t.x - thw, tlty = t.y - thh;
  float trbx = t.x + thw, trby = t.y + thh;

  float iw = fmaxf(fminf(prbx, trbx) - fmaxf(pltx, tltx), 0.f);
  float ih = fmaxf(fminf(prby, trby) - fmaxf(plty, tlty), 0.f);
  float inter = iw * ih;
  float parea = p.z * p.w;
  float tarea = t.z * t.w;
  float iou   = inter / (parea + tarea - inter + EPS);

  float dx = p.x - t.x, dy = p.y - t.y;
  float cd = dx * dx + dy * dy;

  float ew = fmaxf(prbx, trbx) - fminf(pltx, tltx);
  float eh = fmaxf(prby, trby) - fminf(plty, tlty);
  float diag = ew * ew + eh * eh;

  float v = iou - cd / (diag + EPS);

  // wave reduce, then one atomic per wave
  for (int off = 32; off > 0; off >>= 1) v += __shfl_down(v, off, 64);
  if (lane == 0) atomicAdd(acc, v);
}

__global__ void diou_finalize(const float* __restrict__ acc,
                              float* __restrict__ out) {
  out[0] = 1.f - acc[0] * (1.f / (float)NPRED);
}

extern "C" void kernel_launch(void* const* d_in, const int* in_sizes, int n_in,
                              void* d_out, int out_size, void* d_ws, size_t ws_size,
                              hipStream_t stream) {
  const float4* pred = (const float4*)d_in[0];
  const float4* tgt  = (const float4*)d_in[1];

  unsigned long long* pk = (unsigned long long*)d_ws;          // 8192 * 8 B
  float* acc = (float*)((char*)d_ws + NPRED * sizeof(unsigned long long));

  // zero packed-argmax array (key 0 < any real iou key) + accumulator
  hipMemsetAsync(d_ws, 0, NPRED * sizeof(unsigned long long) + 64, stream);

  diou_argmax<<<GRID, BLOCK, 0, stream>>>(pred, tgt, pk);
  diou_gather<<<NPRED / BLOCK, BLOCK, 0, stream>>>(pred, tgt, pk, acc);
  diou_finalize<<<1, 1, 0, stream>>>(acc, (float*)d_out);
}